// Round 5
// baseline (1842.144 us; speedup 1.0000x reference)
//
#include <hip/hip_runtime.h>
#include <math.h>

#define NBATCH 256
#define CDIM   384

typedef __attribute__((ext_vector_type(4))) float  f32x4;
typedef __attribute__((ext_vector_type(8))) __bf16 bf16x8;
typedef __attribute__((ext_vector_type(4))) __bf16 bf16x4;

__device__ __forceinline__ void load16(const void* g, void* l) {
    __builtin_amdgcn_global_load_lds(
        (const __attribute__((address_space(1))) void*)g,
        (__attribute__((address_space(3))) void*)l, 16, 0, 0);
}

// ---------------------------------------------------------------------------
// Gather: target (B,576,384) fp32 -> ta (B,144,384) bf16, pixel-major. float4.
// ---------------------------------------------------------------------------
__global__ __launch_bounds__(256) void gather_bf16(
    const float* __restrict__ target,
    const float* __restrict__ bbox,
    __bf16* __restrict__ ta)
{
    const int b = blockIdx.x, t = threadIdx.x;
    __shared__ int pos[144];

    if (t < 144) {
        const float bx0 = bbox[b * 4 + 0] * 24.f;
        const float by0 = bbox[b * 4 + 1] * 24.f;
        const float bw  = bbox[b * 4 + 2] * 24.f;
        const float bh  = bbox[b * 4 + 3] * 24.f;
        const float l0 = (bw + bh) * 0.5f;
        const float l  = sqrtf((bw + l0) * (bh + l0));
        const int xmin = (int)fminf(fmaxf(ceilf (bx0 - l * 0.5f), 0.f), 23.f);
        const int ymin = (int)fminf(fmaxf(ceilf (by0 - l * 0.5f), 0.f), 23.f);
        const int xmax = (int)fminf(fmaxf(truncf(bx0 + l * 0.5f), 0.f), 23.f);
        const int ymax = (int)fminf(fmaxf(truncf(by0 + l * 0.5f), 0.f), 23.f);
        const int i = t / 12, j = t % 12;
        int r = ymin + (i * (ymax - ymin)) / 12;
        int c = xmin + (j * (xmax - xmin)) / 12;
        r = min(max(r, 0), 23);
        c = min(max(c, 0), 23);
        pos[t] = r * 24 + c;
    }
    __syncthreads();

    const float* tb  = target + (size_t)b * 576 * 384;
    __bf16*      tab = ta     + (size_t)b * 144 * 384;
    for (int idx = t; idx < 144 * 96; idx += 256) {
        const int p = idx / 96, c4 = idx - p * 96;
        const float4 v = *(const float4*)&tb[(size_t)pos[p] * 384 + c4 * 4];
        bf16x4 o = { (__bf16)v.x, (__bf16)v.y, (__bf16)v.z, (__bf16)v.w };
        *(bf16x4*)&tab[(size_t)p * 384 + c4 * 4] = o;
    }
}

// ---------------------------------------------------------------------------
// Weight prep: W (oc, ic, taps) fp32 -> FRAGMENT-MAJOR Wf[ks][oc][kk] bf16,
// ks = tap*12 + jn (jn = ic/32, kk = ic%32). A wave's B-fragment for
// (ks, n-range 16, quad) is then one contiguous, coalesced 1KB region ->
// B is read global->VGPR directly, bypassing LDS.
// ---------------------------------------------------------------------------
template <int TAPS>
__global__ __launch_bounds__(256) void prep_w_frag(
    const float* __restrict__ W, __bf16* __restrict__ Wf)
{
    const int K = TAPS * 384;
    __shared__ float ws[TAPS * 384];
    const int oc = blockIdx.x;
    const float* src = W + (size_t)oc * K;
    for (int i = threadIdx.x; i < K; i += 256) ws[i] = src[i];
    __syncthreads();
    for (int i = threadIdx.x; i < K; i += 256) {
        const int tap = i / 384;
        const int ic  = i - tap * 384;          // ic = jn*32 + kk
        const int jnn = ic >> 5, kk = ic & 31;
        Wf[((size_t)(tap * 12 + jnn) * 384 + oc) * 32 + kk] =
            (__bf16)ws[ic * TAPS + tap];
    }
}

// ---------------------------------------------------------------------------
// Implicit-GEMM conv (tap-decomposed) + BN + leaky (+ residual).
// A: (B*144, 384) bf16 pixel-major (LDS-staged, triple-buffered, 48 KiB).
// B: fragment-major Wf, loaded global->VGPR (L2-resident panel) - LDS traffic
//    per CU-step drops 144->96 KB (the measured 85 B/cyc LDS ceiling was the
//    round-4 wall).
// Loop order j-outer/tap-inner: consecutive steps read the SAME A rows
// (+-1 pixel) and same k-chunk -> A tap re-reads become L2 hits (round-4
// FETCH was 994 MB from 12-step reuse distance).
// BM=256, BN=128, 4 waves of 128x64 (8x4 mfma 16x16x32).
// Counted-vmcnt depth-2 pipeline: raw s_barrier, entry wait vmcnt(8)
// (robust to DMA-group vs B-group issue order), vmcnt(0) on last step.
// ---------------------------------------------------------------------------
template <int TAPS, int KW, int PAD, bool RESID>
__global__ __launch_bounds__(256, 2) void conv_mfma(
    const __bf16* __restrict__ A,
    const __bf16* __restrict__ Wf,
    const float* __restrict__ gg, const float* __restrict__ bb,
    const float* __restrict__ mm, const float* __restrict__ vv,
    const float* __restrict__ temp,
    void* __restrict__ outp)
{
    const int IT = TAPS * 12;          // K-steps of 32 (300 or 108; %3==0)

    // XCD-aware swizzle: contiguous work chunks per XCD (432 = 8*54).
    const int l    = blockIdx.x + 144 * blockIdx.y;
    const int work = (l & 7) * 54 + (l >> 3);
    const int wx   = work % 144, wy = work / 144;
    const int m0   = wx * 256;
    const int n0   = wy * 128;

    const int t  = threadIdx.x;
    const int lane  = t & 63, w = t >> 6;
    const int wm    = (w & 1) * 128, wn = (w >> 1) * 64;
    const int col16 = lane & 15,  quad = lane >> 4;

    __shared__ __bf16 As0[256 * 32], As1[256 * 32], As2[256 * 32];

    // A staging: thread t owns 16B slot (t&3) of rows r0 + 64q; kg swizzles
    // the SOURCE k-group (dest linear, read swizzled - both-sides rule).
    const int r0   = t >> 2, slot = t & 3;
    const int kg   = slot ^ ((r0 >> 1) & 3);

    int yq[4], xq[4];
    const __bf16* Abq[4];
#pragma unroll
    for (int q = 0; q < 4; ++q) {
        const int mrow = m0 + r0 + 64 * q;
        const int b = mrow / 144, p = mrow - b * 144;
        yq[q] = p / 12;
        xq[q] = p - yq[q] * 12;
        Abq[q] = A + (size_t)b * 144 * 384 + kg * 8;
    }

    // loop-invariant swizzled LDS read offsets (elements)
    int offA[8];
#pragma unroll
    for (int mi = 0; mi < 8; ++mi) {
        const int r = wm + mi * 16 + col16;
        offA[mi] = r * 32 + (quad ^ ((r >> 1) & 3)) * 8;
    }
    // loop-invariant B lane offsets (elements within a kslice)
    int loffB[4];
#pragma unroll
    for (int ni = 0; ni < 4; ++ni)
        loffB[ni] = (wn + ni * 16 + col16) * 32 + quad * 8;
    const __bf16* Bbase = Wf + (size_t)n0 * 32;

    f32x4 acc[8][4];
#pragma unroll
    for (int mi = 0; mi < 8; ++mi)
#pragma unroll
        for (int ni = 0; ni < 4; ++ni)
            acc[mi][ni] = (f32x4){0.f, 0.f, 0.f, 0.f};

    // tile-`next` state: j-outer / tap-inner
    int jn = 0, tap = 0, ky = -PAD, kx = -PAD, ksl = 0, next = 0;
    auto advance = [&]() {
        ++tap; ksl += 12; ++kx;
        if (tap == TAPS)          { tap = 0; ++jn; ksl = jn; ky = -PAD; kx = -PAD; }
        else if (kx == KW - PAD)  { kx = -PAD; ++ky; }
    };

    auto issue = [&](__bf16* SA, bf16x8* bvN) {
#pragma unroll
        for (int q = 0; q < 4; ++q) {
            const int sy = min(max(yq[q] + ky, 0), 11);
            const int sx = min(max(xq[q] + kx, 0), 11);
            load16(Abq[q] + (size_t)(sy * 12 + sx) * 384 + jn * 32,
                   &SA[t * 8 + q * 2048]);
        }
        __builtin_amdgcn_sched_barrier(0);   // pin: A-DMA before B-loads
        const __bf16* Bk = Bbase + (size_t)ksl * (384 * 32);
#pragma unroll
        for (int ni = 0; ni < 4; ++ni)
            bvN[ni] = *(const bf16x8*)(Bk + loffB[ni]);
    };

    // One pipeline step: consume (SA, bvC) = tile i; prefetch tile i+2 into
    // (NA, bvN).  vmcnt(8) retires tile i's A-DMA (+B regs) while leaving
    // tile i+1's loads in flight across the barrier.
    auto step = [&](const __bf16* SA, const bf16x8* bvC,
                    __bf16* NA, bf16x8* bvN, bool last) {
        if (last) asm volatile("s_waitcnt vmcnt(0)" ::: "memory");
        else      asm volatile("s_waitcnt vmcnt(8)" ::: "memory");
        __builtin_amdgcn_s_barrier();
        __builtin_amdgcn_sched_barrier(0);
        if (next < IT) { issue(NA, bvN); advance(); ++next; }
        bf16x8 av[8];
#pragma unroll
        for (int mi = 0; mi < 8; ++mi) av[mi] = *(const bf16x8*)&SA[offA[mi]];
        __builtin_amdgcn_s_setprio(1);
#pragma unroll
        for (int mi = 0; mi < 8; ++mi)
#pragma unroll
            for (int ni = 0; ni < 4; ++ni)
                acc[mi][ni] = __builtin_amdgcn_mfma_f32_16x16x32_bf16(
                    av[mi], bvC[ni], acc[mi][ni], 0, 0, 0);
        __builtin_amdgcn_s_setprio(0);
    };

    // prologue: tiles 0 and 1 in flight (A-DMA + B-regs), order pinned
    bf16x8 bv0[4], bv1[4], bv2[4];
    issue(As0, bv0); __builtin_amdgcn_sched_barrier(0); advance(); ++next;
    issue(As1, bv1); __builtin_amdgcn_sched_barrier(0); advance(); ++next;

    for (int it3 = 0; it3 < IT; it3 += 3) {
        step(As0, bv0, As2, bv2, it3 + 1 == IT);
        step(As1, bv1, As0, bv0, it3 + 2 == IT);
        step(As2, bv2, As1, bv1, it3 + 3 == IT);
    }

    // Epilogue: BN + leaky (+ residual).  D: row = quad*4+reg, col = lane&15.
#pragma unroll
    for (int ni = 0; ni < 4; ++ni) {
        const int gn = n0 + wn + ni * 16 + col16;
        const float scale = gg[gn] * rsqrtf(vv[gn] + 1e-5f);
        const float shift = bb[gn] - mm[gn] * scale;
        if (!RESID) {
            __bf16* h1 = (__bf16*)outp;
#pragma unroll
            for (int mi = 0; mi < 8; ++mi) {
                const int gm = m0 + wm + mi * 16 + quad * 4;
#pragma unroll
                for (int r = 0; r < 4; ++r) {
                    float v = acc[mi][ni][r] * scale + shift;
                    v = (v >= 0.f) ? v : 0.01f * v;
                    h1[(size_t)(gm + r) * 384 + gn] = (__bf16)v;
                }
            }
        } else {
            float* outF = (float*)outp;
#pragma unroll
            for (int mi = 0; mi < 8; ++mi) {
                const int gm = m0 + wm + mi * 16 + quad * 4;
#pragma unroll
                for (int r = 0; r < 4; ++r) {
                    float v = acc[mi][ni][r] * scale + shift;
                    v = (v >= 0.f) ? v : 0.01f * v;
                    outF[(size_t)(gm + r) * 384 + gn] =
                        temp[(size_t)(gm + r) * 384 + gn] + v;
                }
            }
        }
    }
}

// ---------------------------------------------------------------------------
extern "C" void kernel_launch(void* const* d_in, const int* in_sizes, int n_in,
                              void* d_out, int out_size, void* d_ws, size_t ws_size,
                              hipStream_t stream) {
    const float* temp   = (const float*)d_in[0];
    const float* target = (const float*)d_in[1];
    const float* bbox   = (const float*)d_in[2];
    const float* W1     = (const float*)d_in[3];
    const float* g1     = (const float*)d_in[4];
    const float* b1     = (const float*)d_in[5];
    const float* m1     = (const float*)d_in[6];
    const float* v1     = (const float*)d_in[7];
    const float* W2     = (const float*)d_in[8];
    const float* g2     = (const float*)d_in[9];
    const float* b2     = (const float*)d_in[10];
    const float* m2     = (const float*)d_in[11];
    const float* v2     = (const float*)d_in[12];
    float* out = (float*)d_out;

    __bf16* ta  = (__bf16*)d_ws;                          // 256*144*384
    __bf16* h1  = ta  + (size_t)NBATCH * 144 * CDIM;      // 256*144*384
    __bf16* Wf1 = h1  + (size_t)NBATCH * 144 * CDIM;      // 300*384*32
    __bf16* Wf2 = Wf1 + (size_t)CDIM * 25 * CDIM;         // 108*384*32

    prep_w_frag<25><<<dim3(CDIM), dim3(256), 0, stream>>>(W1, Wf1);
    prep_w_frag<9><<<dim3(CDIM), dim3(256), 0, stream>>>(W2, Wf2);
    gather_bf16<<<dim3(NBATCH), dim3(256), 0, stream>>>(target, bbox, ta);

    // M = 256*144 = 36864 = 144*256 ; N = 384 = 3*128
    conv_mfma<25, 5, 2, false><<<dim3(144, 3), dim3(256), 0, stream>>>(
        ta, Wf1, g1, b1, m1, v1, nullptr, (void*)h1);
    conv_mfma<9, 3, 1, true><<<dim3(144, 3), dim3(256), 0, stream>>>(
        h1, Wf2, g2, b2, m2, v2, temp, (void*)out);
}

// Round 6
// 1159.177 us; speedup vs baseline: 1.5892x; 1.5892x over previous
//
#include <hip/hip_runtime.h>
#include <math.h>

#define NBATCH 256
#define CDIM   384

typedef __attribute__((ext_vector_type(4))) float  f32x4;
typedef __attribute__((ext_vector_type(8))) __bf16 bf16x8;
typedef __attribute__((ext_vector_type(4))) __bf16 bf16x4;

__device__ __forceinline__ void load16(const void* g, void* l) {
    __builtin_amdgcn_global_load_lds(
        (const __attribute__((address_space(1))) void*)g,
        (__attribute__((address_space(3))) void*)l, 16, 0, 0);
}

// ---------------------------------------------------------------------------
// Gather: target (B,576,384) fp32 -> ta (B,144,384) bf16, pixel-major. float4.
// ---------------------------------------------------------------------------
__global__ __launch_bounds__(256) void gather_bf16(
    const float* __restrict__ target,
    const float* __restrict__ bbox,
    __bf16* __restrict__ ta)
{
    const int b = blockIdx.x, t = threadIdx.x;
    __shared__ int pos[144];

    if (t < 144) {
        const float bx0 = bbox[b * 4 + 0] * 24.f;
        const float by0 = bbox[b * 4 + 1] * 24.f;
        const float bw  = bbox[b * 4 + 2] * 24.f;
        const float bh  = bbox[b * 4 + 3] * 24.f;
        const float l0 = (bw + bh) * 0.5f;
        const float l  = sqrtf((bw + l0) * (bh + l0));
        const int xmin = (int)fminf(fmaxf(ceilf (bx0 - l * 0.5f), 0.f), 23.f);
        const int ymin = (int)fminf(fmaxf(ceilf (by0 - l * 0.5f), 0.f), 23.f);
        const int xmax = (int)fminf(fmaxf(truncf(bx0 + l * 0.5f), 0.f), 23.f);
        const int ymax = (int)fminf(fmaxf(truncf(by0 + l * 0.5f), 0.f), 23.f);
        const int i = t / 12, j = t % 12;
        int r = ymin + (i * (ymax - ymin)) / 12;
        int c = xmin + (j * (xmax - xmin)) / 12;
        r = min(max(r, 0), 23);
        c = min(max(c, 0), 23);
        pos[t] = r * 24 + c;
    }
    __syncthreads();

    const float* tb  = target + (size_t)b * 576 * 384;
    __bf16*      tab = ta     + (size_t)b * 144 * 384;
    for (int idx = t; idx < 144 * 96; idx += 256) {
        const int p = idx / 96, c4 = idx - p * 96;
        const float4 v = *(const float4*)&tb[(size_t)pos[p] * 384 + c4 * 4];
        bf16x4 o = { (__bf16)v.x, (__bf16)v.y, (__bf16)v.z, (__bf16)v.w };
        *(bf16x4*)&tab[(size_t)p * 384 + c4 * 4] = o;
    }
}

// ---------------------------------------------------------------------------
// Weight prep: W (oc, ic, taps) fp32 -> FRAGMENT-MAJOR Wf[ks][oc][kk] bf16,
// ks = tap*12 + jn (jn = ic/32, kk = ic%32). A wave's B-fragment for
// (ks, 16 oc rows, quad) is one contiguous coalesced 1KB region ->
// B is read global->VGPR directly, bypassing LDS.  [verified round 5]
// ---------------------------------------------------------------------------
template <int TAPS>
__global__ __launch_bounds__(256) void prep_w_frag(
    const float* __restrict__ W, __bf16* __restrict__ Wf)
{
    const int K = TAPS * 384;
    __shared__ float ws[TAPS * 384];
    const int oc = blockIdx.x;
    const float* src = W + (size_t)oc * K;
    for (int i = threadIdx.x; i < K; i += 256) ws[i] = src[i];
    __syncthreads();
    for (int i = threadIdx.x; i < K; i += 256) {
        const int tap = i / 384;
        const int ic  = i - tap * 384;          // ic = jn*32 + kk
        const int jnn = ic >> 5, kk = ic & 31;
        Wf[((size_t)(tap * 12 + jnn) * 384 + oc) * 32 + kk] =
            (__bf16)ws[ic * TAPS + tap];
    }
}

// ---------------------------------------------------------------------------
// Implicit-GEMM conv (tap-decomposed) + BN + leaky (+ residual).
// Round-3 proven geometry: BM=BN=128, 4 waves of 64x64 (4x4 mfma 16x16x32),
// triple-buffered counted-vmcnt depth-2 pipeline, raw s_barrier, T5 setprio.
// Changes vs round 3:
//  - B bypasses LDS: fragment-major Wf, global->VGPR into NAMED register
//    buffers via MACROS (round-5's pointer-lambda spilled to scratch;
//    rule #20).  LDS = A only (24 KiB), traffic/blk-step 48->24 KB.
//  - j-outer / tap-inner loop order: consecutive steps reuse the same 8 KB
//    A chunk (L1-resident) -> tap re-reads stop hitting L2/HBM.
//  - bijective XCD swizzle (864 = 8*108): same-n0 blocks share one
//    L2-resident B panel (2.46 MB).
// vmcnt ledger: 6 ops/step (2 A-DMA then 4 B-loads, pinned).  Steady entry
// outstanding = 12 (tiles i, i+1); in-order retirement -> vmcnt(10) retires
// exactly tile i's A-DMA.  Compiler inserts its own waits for bv uses.
// ---------------------------------------------------------------------------
template <int TAPS, int KW, int PAD, bool RESID>
__global__ __launch_bounds__(256, 3) void conv_mfma(
    const __bf16* __restrict__ A,
    const __bf16* __restrict__ Wf,
    const float* __restrict__ gg, const float* __restrict__ bb,
    const float* __restrict__ mm, const float* __restrict__ vv,
    const float* __restrict__ temp,
    void* __restrict__ outp)
{
    const int IT = TAPS * 12;          // K-steps of 32 (300 or 108; %3==0)

    // XCD-aware bijective swizzle: 864 = 8 * 108 contiguous works per XCD.
    const int l    = blockIdx.x + 288 * blockIdx.y;
    const int work = (l & 7) * 108 + (l >> 3);
    const int wx   = work % 288, wy = work / 288;
    const int m0   = wx * 128;
    const int n0   = wy * 128;

    const int t  = threadIdx.x;
    const int lane  = t & 63, w = t >> 6;
    const int wm    = (w & 1) * 64, wn = (w >> 1) * 64;
    const int col16 = lane & 15,  quad = lane >> 4;

    __shared__ __bf16 As0[128 * 32], As1[128 * 32], As2[128 * 32];

    // A staging: thread t owns 16B slot (t&3) of rows r0, r0+64; kg swizzles
    // the SOURCE k-group (dest linear, read swizzled - both-sides rule).
    const int r0   = t >> 2, slot = t & 3;
    const int kg   = slot ^ ((r0 >> 1) & 3);
    const int mrow0 = m0 + r0, mrow1 = m0 + r0 + 64;
    const int b0 = mrow0 / 144, p0 = mrow0 - b0 * 144;
    const int b1 = mrow1 / 144, p1 = mrow1 - b1 * 144;
    const int y0 = p0 / 12, x0 = p0 - y0 * 12;
    const int y1 = p1 / 12, x1 = p1 - y1 * 12;
    const __bf16* Ab0 = A + (size_t)b0 * 144 * 384 + kg * 8;
    const __bf16* Ab1 = A + (size_t)b1 * 144 * 384 + kg * 8;

    // loop-invariant swizzled LDS read offsets (elements)
    int offA[4];
#pragma unroll
    for (int mi = 0; mi < 4; ++mi) {
        const int r = wm + mi * 16 + col16;
        offA[mi] = r * 32 + (quad ^ ((r >> 1) & 3)) * 8;
    }
    // loop-invariant B lane offsets (elements within a k-slice of Wf)
    const int loffB0 = (wn + 0 * 16 + col16) * 32 + quad * 8;
    const int loffB1 = (wn + 1 * 16 + col16) * 32 + quad * 8;
    const int loffB2 = (wn + 2 * 16 + col16) * 32 + quad * 8;
    const int loffB3 = (wn + 3 * 16 + col16) * 32 + quad * 8;
    const __bf16* Bbase = Wf + (size_t)n0 * 32;

    f32x4 acc[4][4];
#pragma unroll
    for (int mi = 0; mi < 4; ++mi)
#pragma unroll
        for (int ni = 0; ni < 4; ++ni)
            acc[mi][ni] = (f32x4){0.f, 0.f, 0.f, 0.f};

    // tile-`next` state: j-outer / tap-inner
    int jn = 0, tap = 0, ky = -PAD, kx = -PAD, ksl = 0, next = 0;
    auto advance = [&]() {
        ++tap; ksl += 12; ++kx;
        if (tap == TAPS)         { tap = 0; ++jn; ksl = jn; ky = -PAD; kx = -PAD; }
        else if (kx == PAD + 1)  { kx = -PAD; ++ky; }
    };

    // Named register buffers for B fragments (NEVER address-taken).
    bf16x8 bv0_0, bv0_1, bv0_2, bv0_3;
    bf16x8 bv1_0, bv1_1, bv1_2, bv1_3;
    bf16x8 bv2_0, bv2_1, bv2_2, bv2_3;

#define ISSUE(SA, B_)                                                         \
    do {                                                                      \
        const int sy0 = min(max(y0 + ky, 0), 11), sx0 = min(max(x0 + kx, 0), 11); \
        const int sy1 = min(max(y1 + ky, 0), 11), sx1 = min(max(x1 + kx, 0), 11); \
        load16(Ab0 + (size_t)(sy0 * 12 + sx0) * 384 + jn * 32, &SA[t * 8]);   \
        load16(Ab1 + (size_t)(sy1 * 12 + sx1) * 384 + jn * 32, &SA[(t + 256) * 8]); \
        __builtin_amdgcn_sched_barrier(0);  /* pin: A-DMA before B-loads */   \
        const __bf16* Bk = Bbase + (size_t)ksl * (384 * 32);                  \
        B_##_0 = *(const bf16x8*)(Bk + loffB0);                               \
        B_##_1 = *(const bf16x8*)(Bk + loffB1);                               \
        B_##_2 = *(const bf16x8*)(Bk + loffB2);                               \
        B_##_3 = *(const bf16x8*)(Bk + loffB3);                               \
    } while (0)

#define STEP(SA, B_, NA, NB_, last)                                           \
    do {                                                                      \
        if (last) asm volatile("s_waitcnt vmcnt(0)" ::: "memory");            \
        else      asm volatile("s_waitcnt vmcnt(10)" ::: "memory");           \
        __builtin_amdgcn_s_barrier();                                         \
        __builtin_amdgcn_sched_barrier(0);                                    \
        if (next < IT) { ISSUE(NA, NB_); advance(); ++next; }                 \
        bf16x8 av0 = *(const bf16x8*)&SA[offA[0]];                            \
        bf16x8 av1 = *(const bf16x8*)&SA[offA[1]];                            \
        bf16x8 av2 = *(const bf16x8*)&SA[offA[2]];                            \
        bf16x8 av3 = *(const bf16x8*)&SA[offA[3]];                            \
        __builtin_amdgcn_s_setprio(1);                                        \
        acc[0][0] = __builtin_amdgcn_mfma_f32_16x16x32_bf16(av0, B_##_0, acc[0][0], 0, 0, 0); \
        acc[0][1] = __builtin_amdgcn_mfma_f32_16x16x32_bf16(av0, B_##_1, acc[0][1], 0, 0, 0); \
        acc[0][2] = __builtin_amdgcn_mfma_f32_16x16x32_bf16(av0, B_##_2, acc[0][2], 0, 0, 0); \
        acc[0][3] = __builtin_amdgcn_mfma_f32_16x16x32_bf16(av0, B_##_3, acc[0][3], 0, 0, 0); \
        acc[1][0] = __builtin_amdgcn_mfma_f32_16x16x32_bf16(av1, B_##_0, acc[1][0], 0, 0, 0); \
        acc[1][1] = __builtin_amdgcn_mfma_f32_16x16x32_bf16(av1, B_##_1, acc[1][1], 0, 0, 0); \
        acc[1][2] = __builtin_amdgcn_mfma_f32_16x16x32_bf16(av1, B_##_2, acc[1][2], 0, 0, 0); \
        acc[1][3] = __builtin_amdgcn_mfma_f32_16x16x32_bf16(av1, B_##_3, acc[1][3], 0, 0, 0); \
        acc[2][0] = __builtin_amdgcn_mfma_f32_16x16x32_bf16(av2, B_##_0, acc[2][0], 0, 0, 0); \
        acc[2][1] = __builtin_amdgcn_mfma_f32_16x16x32_bf16(av2, B_##_1, acc[2][1], 0, 0, 0); \
        acc[2][2] = __builtin_amdgcn_mfma_f32_16x16x32_bf16(av2, B_##_2, acc[2][2], 0, 0, 0); \
        acc[2][3] = __builtin_amdgcn_mfma_f32_16x16x32_bf16(av2, B_##_3, acc[2][3], 0, 0, 0); \
        acc[3][0] = __builtin_amdgcn_mfma_f32_16x16x32_bf16(av3, B_##_0, acc[3][0], 0, 0, 0); \
        acc[3][1] = __builtin_amdgcn_mfma_f32_16x16x32_bf16(av3, B_##_1, acc[3][1], 0, 0, 0); \
        acc[3][2] = __builtin_amdgcn_mfma_f32_16x16x32_bf16(av3, B_##_2, acc[3][2], 0, 0, 0); \
        acc[3][3] = __builtin_amdgcn_mfma_f32_16x16x32_bf16(av3, B_##_3, acc[3][3], 0, 0, 0); \
        __builtin_amdgcn_s_setprio(0);                                        \
    } while (0)

    // prologue: tiles 0 and 1 in flight
    ISSUE(As0, bv0); advance(); ++next;
    ISSUE(As1, bv1); advance(); ++next;

    for (int it3 = 0; it3 < IT; it3 += 3) {
        STEP(As0, bv0, As2, bv2, it3 + 1 == IT);
        STEP(As1, bv1, As0, bv0, it3 + 2 == IT);
        STEP(As2, bv2, As1, bv1, it3 + 3 == IT);
    }
#undef STEP
#undef ISSUE

    // Epilogue: BN + leaky (+ residual).  D: row = quad*4+reg, col = lane&15.
#pragma unroll
    for (int ni = 0; ni < 4; ++ni) {
        const int gn = n0 + wn + ni * 16 + col16;
        const float scale = gg[gn] * rsqrtf(vv[gn] + 1e-5f);
        const float shift = bb[gn] - mm[gn] * scale;
        if (!RESID) {
            __bf16* h1 = (__bf16*)outp;
#pragma unroll
            for (int mi = 0; mi < 4; ++mi) {
                const int gm = m0 + wm + mi * 16 + quad * 4;
#pragma unroll
                for (int r = 0; r < 4; ++r) {
                    float v = acc[mi][ni][r] * scale + shift;
                    v = (v >= 0.f) ? v : 0.01f * v;
                    h1[(size_t)(gm + r) * 384 + gn] = (__bf16)v;
                }
            }
        } else {
            float* outF = (float*)outp;
#pragma unroll
            for (int mi = 0; mi < 4; ++mi) {
                const int gm = m0 + wm + mi * 16 + quad * 4;
#pragma unroll
                for (int r = 0; r < 4; ++r) {
                    float v = acc[mi][ni][r] * scale + shift;
                    v = (v >= 0.f) ? v : 0.01f * v;
                    outF[(size_t)(gm + r) * 384 + gn] =
                        temp[(size_t)(gm + r) * 384 + gn] + v;
                }
            }
        }
    }
}

// ---------------------------------------------------------------------------
extern "C" void kernel_launch(void* const* d_in, const int* in_sizes, int n_in,
                              void* d_out, int out_size, void* d_ws, size_t ws_size,
                              hipStream_t stream) {
    const float* temp   = (const float*)d_in[0];
    const float* target = (const float*)d_in[1];
    const float* bbox   = (const float*)d_in[2];
    const float* W1     = (const float*)d_in[3];
    const float* g1     = (const float*)d_in[4];
    const float* b1     = (const float*)d_in[5];
    const float* m1     = (const float*)d_in[6];
    const float* v1     = (const float*)d_in[7];
    const float* W2     = (const float*)d_in[8];
    const float* g2     = (const float*)d_in[9];
    const float* b2     = (const float*)d_in[10];
    const float* m2     = (const float*)d_in[11];
    const float* v2     = (const float*)d_in[12];
    float* out = (float*)d_out;

    __bf16* ta  = (__bf16*)d_ws;                          // 256*144*384
    __bf16* h1  = ta  + (size_t)NBATCH * 144 * CDIM;      // 256*144*384
    __bf16* Wf1 = h1  + (size_t)NBATCH * 144 * CDIM;      // 300*384*32
    __bf16* Wf2 = Wf1 + (size_t)CDIM * 25 * CDIM;         // 108*384*32

    prep_w_frag<25><<<dim3(CDIM), dim3(256), 0, stream>>>(W1, Wf1);
    prep_w_frag<9><<<dim3(CDIM), dim3(256), 0, stream>>>(W2, Wf2);
    gather_bf16<<<dim3(NBATCH), dim3(256), 0, stream>>>(target, bbox, ta);

    // M = 256*144 = 36864 = 288*128 ; N = 384 = 3*128
    conv_mfma<25, 5, 2, false><<<dim3(288, 3), dim3(256), 0, stream>>>(
        ta, Wf1, g1, b1, m1, v1, nullptr, (void*)h1);
    conv_mfma<9, 3, 1, true><<<dim3(288, 3), dim3(256), 0, stream>>>(
        h1, Wf2, g2, b2, m2, v2, temp, (void*)out);
}